// Round 6
// baseline (599.041 us; speedup 1.0000x reference)
//
#include <hip/hip_runtime.h>
#include <math.h>

// Mesh encoder: 4x (spiral conv + ELU + sparse pool) + final GEMM.
// VERTS = [65536, 16384, 4096, 1024, 256], SEQ=9, CH=[3,32,64,128,256], B=16.
//
// R5: wave-per-edge MFMA conv (16x16x32 bf16, M=16 batches), 3-MFMA hi/lo
// error split, atomic pool-scatter in [b][r][co] layout, no CSR/LDS/barriers.
// R6: co-split CS via grid.y (wave handles COUT/CS couts) — L2/L3 were
// parallelism-starved (768 waves on 1024 SIMDs, occupancy 8.6%).

#define SEQL 9

typedef __attribute__((ext_vector_type(8))) short bf16x8;
typedef __attribute__((ext_vector_type(4))) float f32x4;

__device__ __forceinline__ unsigned short f2bf_rne(float f) {
    unsigned u = __builtin_bit_cast(unsigned, f);
    u = (u + 0x7FFFu + ((u >> 16) & 1u)) >> 16;
    return (unsigned short)u;
}
__device__ __forceinline__ float bf2f(unsigned short h) {
    unsigned u = ((unsigned)h) << 16;
    return __builtin_bit_cast(float, u);
}

// x [16][65536][3] -> xT [65536][3][16]
__global__ __launch_bounds__(256)
void transpose_x0(const float* __restrict__ x, float* __restrict__ xT)
{
    const int f = blockIdx.x * 256 + threadIdx.x;   // 65536*48
    const int v = f / 48, rem = f % 48;
    const int c = rem / 16, b = rem % 16;
    xT[f] = x[((size_t)b * 65536 + v) * 3 + c];
}

// W [9*CIN][COUT] fp32 -> WTh/WTl [COUT][K] bf16 (K padded to mult of 32).
template<int CIN, int COUT>
__global__ __launch_bounds__(256)
void wt_prep(const float* __restrict__ W, unsigned short* __restrict__ WTh,
             unsigned short* __restrict__ WTl)
{
    constexpr int K9 = 9 * CIN;
    constexpr int K  = ((K9 + 31) / 32) * 32;
    const int t = blockIdx.x * 256 + threadIdx.x;
    const int co = t / K, k = t % K;
    float w = (k < K9) ? W[(size_t)k * COUT + co] : 0.0f;
    unsigned short h = f2bf_rne(w);
    WTh[t] = h;
    WTl[t] = f2bf_rne(w - bf2f(h));
}

// One wave per (edge, co-split): conv for 16 batches x (COUT/CS) couts via
// MFMA, ELU, scale, atomicAdd into xout[b][row[e]][co].
template<int CIN, int COUT, int CS>
__global__ __launch_bounds__(256)
void conv_pool_mfma(const float* __restrict__ xin,
                    const int* __restrict__ idx,    // [NV][9]
                    const int* __restrict__ col, const int* __restrict__ row,
                    const float* __restrict__ val,
                    const unsigned short* __restrict__ WTh,
                    const unsigned short* __restrict__ WTl,
                    const float* __restrict__ bias,
                    float* __restrict__ xout,       // [16][NVOUT][COUT], zeroed
                    int NV, int NVOUT, int nnz)
{
    constexpr int K9 = 9 * CIN;
    constexpr int KSTEPS = (K9 + 31) / 32;
    constexpr int K = KSTEPS * 32;
    constexpr int NT = COUT / 16 / CS;   // co-tiles per wave

    const int lane = threadIdx.x & 63;
    const int wid  = threadIdx.x >> 6;
    const int e    = blockIdx.x * 4 + wid;
    if (e >= nnz) return;
    const int co0  = blockIdx.y * NT * 16;

    const int   v  = col[e];
    const int   r  = row[e];
    const float vv = val[e];
    const int b16 = lane & 15;   // A row (batch) / B col (co_local)
    const int g   = lane >> 4;   // k-slot group

    f32x4 acc[NT];
#pragma unroll
    for (int nt = 0; nt < NT; ++nt) {
        const float bv = bias[co0 + nt * 16 + b16];
        acc[nt] = (f32x4){bv, bv, bv, bv};
    }

#pragma unroll 1
    for (int ks = 0; ks < KSTEPS; ++ks) {
        bf16x8 ah, al;
        if constexpr (CIN >= 32) {
            constexpr int KPS = CIN / 32;
            const int s  = ks / KPS;
            const int c0 = (ks % KPS) * 32 + g * 8;
            const int vi = idx[v * SEQL + s];
            const float* xp = xin + ((size_t)b16 * NV + vi) * CIN + c0;
            const float4 x0 = *(const float4*)xp;
            const float4 x1 = *(const float4*)(xp + 4);
            const float xf[8] = {x0.x, x0.y, x0.z, x0.w, x1.x, x1.y, x1.z, x1.w};
#pragma unroll
            for (int j = 0; j < 8; ++j) {
                const unsigned short h = f2bf_rne(xf[j]);
                ah[j] = (short)h;
                al[j] = (short)f2bf_rne(xf[j] - bf2f(h));
            }
        } else {
            // CIN==3, K9=27: slots k>=27 zero (WT pad rows are 0 too)
#pragma unroll
            for (int j = 0; j < 8; ++j) {
                const int k = g * 8 + j;
                float xf = 0.0f;
                if (k < K9) {
                    const int s = k / 3;
                    const int c = k - 3 * s;
                    const int vi = idx[v * SEQL + s];
                    xf = xin[(size_t)vi * 48 + c * 16 + b16];
                }
                const unsigned short h = f2bf_rne(xf);
                ah[j] = (short)h;
                al[j] = (short)f2bf_rne(xf - bf2f(h));
            }
        }
#pragma unroll
        for (int nt = 0; nt < NT; ++nt) {
            const size_t wo = (size_t)(co0 + nt * 16 + b16) * K + ks * 32 + g * 8;
            const bf16x8 bh = *(const bf16x8*)(WTh + wo);
            const bf16x8 bl = *(const bf16x8*)(WTl + wo);
            // (ah+al)*(bh+bl) ~= ah*bh + al*bh + ah*bl  (al*bl dropped)
            acc[nt] = __builtin_amdgcn_mfma_f32_16x16x32_bf16(ah, bh, acc[nt], 0, 0, 0);
            acc[nt] = __builtin_amdgcn_mfma_f32_16x16x32_bf16(al, bh, acc[nt], 0, 0, 0);
            acc[nt] = __builtin_amdgcn_mfma_f32_16x16x32_bf16(ah, bl, acc[nt], 0, 0, 0);
        }
    }

    // D: row=(lane>>4)*4+reg (batch), col=lane&15 (co_local) [m89-verified]
#pragma unroll
    for (int nt = 0; nt < NT; ++nt)
#pragma unroll
        for (int q = 0; q < 4; ++q) {
            const int b = g * 4 + q;
            float y = acc[nt][q];
            y = (y > 0.0f) ? y : __expf(y) - 1.0f;
            atomicAdd(xout + ((size_t)b * NVOUT + r) * COUT + co0 + nt * 16 + b16, vv * y);
        }
}

// Final GEMM partials: part[jblk][b][l] = sum_{j in blk} x4[b][j]*Wf[j][l]
__global__ __launch_bounds__(256)
void final_gemm_partial(const float* __restrict__ x4,   // [16][65536]
                        const float* __restrict__ Wf,   // [65536][256]
                        float* __restrict__ part)       // [256][16][256]
{
    __shared__ float xs[256 * 20];
    const int j0 = blockIdx.x * 256;
    const int t  = threadIdx.x;

#pragma unroll
    for (int it = 0; it < 16; ++it)
        xs[t * 20 + it] = x4[(size_t)it * 65536 + j0 + t];
    __syncthreads();

    float acc[16];
#pragma unroll
    for (int b = 0; b < 16; ++b) acc[b] = 0.0f;

#pragma unroll 4
    for (int jj = 0; jj < 256; ++jj) {
        const float w = Wf[(size_t)(j0 + jj) * 256 + t];
#pragma unroll
        for (int b4 = 0; b4 < 4; ++b4) {
            const float4 xv = *(const float4*)(xs + jj * 20 + b4 * 4);
            acc[b4 * 4 + 0] = fmaf(xv.x, w, acc[b4 * 4 + 0]);
            acc[b4 * 4 + 1] = fmaf(xv.y, w, acc[b4 * 4 + 1]);
            acc[b4 * 4 + 2] = fmaf(xv.z, w, acc[b4 * 4 + 2]);
            acc[b4 * 4 + 3] = fmaf(xv.w, w, acc[b4 * 4 + 3]);
        }
    }
#pragma unroll
    for (int b = 0; b < 16; ++b)
        part[(size_t)blockIdx.x * 4096 + b * 256 + t] = acc[b];
}

__global__ __launch_bounds__(256)
void final_reduce(const float* __restrict__ part, const float* __restrict__ bf,
                  float* __restrict__ out)
{
    const int b = blockIdx.x, l = threadIdx.x;   // 16 x 256
    float s = 0.0f;
    for (int jb = 0; jb < 256; ++jb) s += part[(size_t)jb * 4096 + b * 256 + l];
    out[b * 256 + l] = s + bf[l];
}

extern "C" void kernel_launch(void* const* d_in, const int* in_sizes, int n_in,
                              void* d_out, int out_size, void* d_ws, size_t ws_size,
                              hipStream_t stream)
{
    const float* x    = (const float*)d_in[0];
    const int*   idx0 = (const int*)d_in[1];
    const int*   row0 = (const int*)d_in[2];
    const int*   col0 = (const int*)d_in[3];
    const float* val0 = (const float*)d_in[4];
    const float* W0   = (const float*)d_in[5];
    const float* b0   = (const float*)d_in[6];
    const int*   idx1 = (const int*)d_in[7];
    const int*   row1 = (const int*)d_in[8];
    const int*   col1 = (const int*)d_in[9];
    const float* val1 = (const float*)d_in[10];
    const float* W1   = (const float*)d_in[11];
    const float* b1   = (const float*)d_in[12];
    const int*   idx2 = (const int*)d_in[13];
    const int*   row2 = (const int*)d_in[14];
    const int*   col2 = (const int*)d_in[15];
    const float* val2 = (const float*)d_in[16];
    const float* W2   = (const float*)d_in[17];
    const float* b2   = (const float*)d_in[18];
    const int*   idx3 = (const int*)d_in[19];
    const int*   row3 = (const int*)d_in[20];
    const int*   col3 = (const int*)d_in[21];
    const float* val3 = (const float*)d_in[22];
    const float* W3   = (const float*)d_in[23];
    const float* b3   = (const float*)d_in[24];
    const float* Wf   = (const float*)d_in[25];
    const float* bf   = (const float*)d_in[26];
    float* out = (float*)d_out;

    float* ws = (float*)d_ws;
    // Aliased timeline (float offsets), peak 51.9 MB:
    float* x1   = ws + 0;         // [16][16384][32]  live L0->L1
    float* xT0  = ws + 8388608;   // [65536][3][16]   live pre->L0
    float* x2   = ws + 8388608;   // [16][4096][64]   live L1->L2 (zeroed post-L0)
    float* x3   = ws + 0;         // [16][1024][128]  live L2->L3 (zeroed post-L1)
    float* x4   = ws + 2097152;   // [16][256][256]   live L3->final
    float* part = ws + 3145728;   // [256][16][256]   final phase
    unsigned short* wt = (unsigned short*)(ws + 12582912);
    unsigned short *WTh0 = wt,            *WTl0 = wt + 1024;
    unsigned short *WTh1 = wt + 2048,     *WTl1 = wt + 20480;
    unsigned short *WTh2 = wt + 38912,    *WTl2 = wt + 112640;
    unsigned short *WTh3 = wt + 186368,   *WTl3 = wt + 481280;   // end 776192 u16

    // weight prep (tiny)
    wt_prep<3,   32><<<   4, 256, 0, stream>>>(W0, WTh0, WTl0);
    wt_prep<32,  64><<<  72, 256, 0, stream>>>(W1, WTh1, WTl1);
    wt_prep<64, 128><<< 288, 256, 0, stream>>>(W2, WTh2, WTl2);
    wt_prep<128,256><<<1152, 256, 0, stream>>>(W3, WTh3, WTl3);

    // L0
    hipMemsetAsync(x1, 0, (size_t)8388608 * 4, stream);
    transpose_x0<<<12288, 256, 0, stream>>>(x, xT0);
    conv_pool_mfma<3, 32, 1><<<dim3(12288, 1), 256, 0, stream>>>(
        xT0, idx0, col0, row0, val0, WTh0, WTl0, b0, x1, 65536, 16384, 49152);

    // L1
    hipMemsetAsync(x2, 0, (size_t)4194304 * 4, stream);   // xT0 dead
    conv_pool_mfma<32, 64, 2><<<dim3(3072, 2), 256, 0, stream>>>(
        x1, idx1, col1, row1, val1, WTh1, WTl1, b1, x2, 16384, 4096, 12288);

    // L2 + L3 (x1 dead -> zero x3|x4 region in one go)
    hipMemsetAsync(x3, 0, (size_t)3145728 * 4, stream);
    conv_pool_mfma<64, 128, 4><<<dim3(768, 4), 256, 0, stream>>>(
        x2, idx2, col2, row2, val2, WTh2, WTl2, b2, x3, 4096, 1024, 3072);
    conv_pool_mfma<128, 256, 8><<<dim3(192, 8), 256, 0, stream>>>(
        x3, idx3, col3, row3, val3, WTh3, WTl3, b3, x4, 1024, 256, 768);

    // final GEMM: out[16,256] = bf + x4_flat[16,65536] @ Wf[65536,256]
    final_gemm_partial<<<256, 256, 0, stream>>>(x4, Wf, part);
    final_reduce<<<16, 256, 0, stream>>>(part, bf, out);
}

// Round 7
// 418.986 us; speedup vs baseline: 1.4297x; 1.4297x over previous
//
#include <hip/hip_runtime.h>
#include <math.h>

// Mesh encoder: 4x (spiral conv + ELU + sparse pool) + final GEMM.
// VERTS = [65536, 16384, 4096, 1024, 256], SEQ=9, CH=[3,32,64,128,256], B=16.
//
// R7: M-rows = 16 edges x 1 batch; batch->XCD pinning via bid%8 so each
// XCD's random spiral gathers hit its own L2 (per-batch x-slice 0.5-2.1 MB);
// ES edge-groups per wave reuse W registers (W L2 traffic / ES); cheap
// truncation-based hi/lo bf16 split packed with v_perm_b32 (3 VALU/elem);
// 3-MFMA error-split retained (x*W ~ ah*bh + al*bh + ah*bl).

#define SEQL 9

typedef __attribute__((ext_vector_type(8))) short bf16x8;
typedef __attribute__((ext_vector_type(4))) float f32x4;

__device__ __forceinline__ unsigned short f2bf_rne(float f) {
    unsigned u = __builtin_bit_cast(unsigned, f);
    u = (u + 0x7FFFu + ((u >> 16) & 1u)) >> 16;
    return (unsigned short)u;
}
__device__ __forceinline__ float bf2f(unsigned short h) {
    unsigned u = ((unsigned)h) << 16;
    return __builtin_bit_cast(float, u);
}

// split 8 fp32 -> bf16 hi (trunc) + bf16 lo (trunc of exact residual)
__device__ __forceinline__ void cvt8(const float* xf, bf16x8& ah, bf16x8& al) {
    unsigned hu[4], lu[4];
#pragma unroll
    for (int p = 0; p < 4; ++p) {
        const unsigned u0 = __builtin_bit_cast(unsigned, xf[2 * p]);
        const unsigned u1 = __builtin_bit_cast(unsigned, xf[2 * p + 1]);
        const float h0 = __builtin_bit_cast(float, u0 & 0xFFFF0000u);
        const float h1 = __builtin_bit_cast(float, u1 & 0xFFFF0000u);
        const float l0 = xf[2 * p] - h0;       // exact (Sterbenz)
        const float l1 = xf[2 * p + 1] - h1;
        hu[p] = __builtin_amdgcn_perm(u1, u0, 0x07060302u);
        lu[p] = __builtin_amdgcn_perm(__builtin_bit_cast(unsigned, l1),
                                      __builtin_bit_cast(unsigned, l0),
                                      0x07060302u);
    }
    struct U4 { unsigned a, b, c, d; };
    ah = __builtin_bit_cast(bf16x8, U4{hu[0], hu[1], hu[2], hu[3]});
    al = __builtin_bit_cast(bf16x8, U4{lu[0], lu[1], lu[2], lu[3]});
}

// W [9*CIN][COUT] fp32 -> WTh/WTl [COUT][K] bf16; k -> (s = k/CINP, c = k%CINP),
// zero-padded where s>=9 or c>=CIN.
template<int CIN, int CINP, int COUT, int K>
__global__ __launch_bounds__(256)
void wt_prep(const float* __restrict__ W, unsigned short* __restrict__ WTh,
             unsigned short* __restrict__ WTl)
{
    const int t = blockIdx.x * 256 + threadIdx.x;
    if (t >= COUT * K) return;
    const int co = t / K, k = t % K;
    const int s = k / CINP, c = k % CINP;
    float w = (s < 9 && c < CIN) ? W[(size_t)(s * CIN + c) * COUT + co] : 0.0f;
    unsigned short h = f2bf_rne(w);
    WTh[t] = h;
    WTl[t] = f2bf_rne(w - bf2f(h));
}

// Wave = ES groups of 16 edges x 1 batch x CS-slice of couts.
// A rows = 16 edges (lane&15), k = (lane>>4)*8 + j within a 32-k step
// (same consistent A/B k-mapping that passed R5/R6). W regs loaded once per
// k-step and reused across ES edge-groups.
// bid = q + 8*(egb + EGB*cs ... ) decoded so bid%8 == batch%8 (XCD pinning).
template<int CIN, int CINP, int COUT, int K, int ES, int CS, int BPB>
__global__ __launch_bounds__(256)
void conv_pool_mfma(const float* __restrict__ xin,   // [16][NV][CIN]
                    const int* __restrict__ idx,     // [NV][9]
                    const int* __restrict__ col, const int* __restrict__ row,
                    const float* __restrict__ val,
                    const unsigned short* __restrict__ WTh,
                    const unsigned short* __restrict__ WTl,
                    const float* __restrict__ bias,
                    float* __restrict__ xout,        // [16][NVOUT][COUT], zeroed
                    int NV, int NVOUT)
{
    constexpr int NT  = COUT / 16 / CS;
    constexpr int EGB = BPB / CS;

    const int tid  = threadIdx.x;
    const int lane = tid & 63, wid = tid >> 6;
    const int b16  = lane & 15, g = lane >> 4;

    const int bid  = blockIdx.x;
    const int q    = bid & 7, rr = bid >> 3;
    const int pass = rr / BPB, j = rr % BPB;
    const int b    = q + 8 * pass;                  // batch
    const int cs   = j / EGB, egb = j % EGB;
    const int co0  = cs * (NT * 16);
    const int wg   = egb * 4 + wid;                 // wave-group in (b, cs)
    const int e_base = wg * (ES * 16);

    int cl[ES];
#pragma unroll
    for (int es = 0; es < ES; ++es) cl[es] = col[e_base + es * 16 + b16];

    f32x4 acc[ES][NT];
#pragma unroll
    for (int es = 0; es < ES; ++es)
#pragma unroll
        for (int nt = 0; nt < NT; ++nt) {
            const float bv = bias[co0 + nt * 16 + b16];
            acc[es][nt] = (f32x4){bv, bv, bv, bv};
        }

    if constexpr (CINP == 4) {
        // L0 (CIN=3): K=64, 2 k-steps; lane j: s = ks*8 + g*2 + j/4, c = j%4
#pragma unroll
        for (int ks = 0; ks < 2; ++ks) {
            bf16x8 wh[NT], wl[NT];
#pragma unroll
            for (int nt = 0; nt < NT; ++nt) {
                const size_t wo = (size_t)(co0 + nt * 16 + b16) * K + ks * 32 + g * 8;
                wh[nt] = *(const bf16x8*)(WTh + wo);
                wl[nt] = *(const bf16x8*)(WTl + wo);
            }
#pragma unroll
            for (int es = 0; es < ES; ++es) {
                const int s0 = ks * 8 + g * 2;
                const int vi0 = (s0     < 9) ? idx[cl[es] * SEQL + s0]     : 0;
                const int vi1 = (s0 + 1 < 9) ? idx[cl[es] * SEQL + s0 + 1] : 0;
                const float* p0 = xin + ((size_t)b * NV + vi0) * 3;
                const float* p1 = xin + ((size_t)b * NV + vi1) * 3;
                float xf[8];
                xf[0] = p0[0]; xf[1] = p0[1]; xf[2] = p0[2]; xf[3] = 0.0f;
                xf[4] = p1[0]; xf[5] = p1[1]; xf[6] = p1[2]; xf[7] = 0.0f;
                if (s0     >= 9) { xf[0] = xf[1] = xf[2] = 0.0f; }
                if (s0 + 1 >= 9) { xf[4] = xf[5] = xf[6] = 0.0f; }
                bf16x8 ah, al; cvt8(xf, ah, al);
#pragma unroll
                for (int nt = 0; nt < NT; ++nt) {
                    acc[es][nt] = __builtin_amdgcn_mfma_f32_16x16x32_bf16(ah, wh[nt], acc[es][nt], 0, 0, 0);
                    acc[es][nt] = __builtin_amdgcn_mfma_f32_16x16x32_bf16(al, wh[nt], acc[es][nt], 0, 0, 0);
                    acc[es][nt] = __builtin_amdgcn_mfma_f32_16x16x32_bf16(ah, wl[nt], acc[es][nt], 0, 0, 0);
                }
            }
        }
    } else {
        constexpr int KPS = CIN / 32;
#pragma unroll 1
        for (int s = 0; s < SEQL; ++s) {
            int vi[ES];
#pragma unroll
            for (int es = 0; es < ES; ++es) vi[es] = idx[cl[es] * SEQL + s];
#pragma unroll
            for (int kk = 0; kk < KPS; ++kk) {
                const int ksl = s * KPS + kk;
                bf16x8 wh[NT], wl[NT];
#pragma unroll
                for (int nt = 0; nt < NT; ++nt) {
                    const size_t wo = (size_t)(co0 + nt * 16 + b16) * K + ksl * 32 + g * 8;
                    wh[nt] = *(const bf16x8*)(WTh + wo);
                    wl[nt] = *(const bf16x8*)(WTl + wo);
                }
#pragma unroll
                for (int es = 0; es < ES; ++es) {
                    const float* xp = xin + ((size_t)b * NV + vi[es]) * CIN + kk * 32 + g * 8;
                    float xf[8];
                    *(float4*)&xf[0] = *(const float4*)xp;
                    *(float4*)&xf[4] = *(const float4*)(xp + 4);
                    bf16x8 ah, al; cvt8(xf, ah, al);
#pragma unroll
                    for (int nt = 0; nt < NT; ++nt) {
                        acc[es][nt] = __builtin_amdgcn_mfma_f32_16x16x32_bf16(ah, wh[nt], acc[es][nt], 0, 0, 0);
                        acc[es][nt] = __builtin_amdgcn_mfma_f32_16x16x32_bf16(al, wh[nt], acc[es][nt], 0, 0, 0);
                        acc[es][nt] = __builtin_amdgcn_mfma_f32_16x16x32_bf16(ah, wl[nt], acc[es][nt], 0, 0, 0);
                    }
                }
            }
        }
    }

    // D: col=lane&15 (co_local), row=(lane>>4)*4+reg (edge m-row) [m89]
#pragma unroll
    for (int es = 0; es < ES; ++es)
#pragma unroll
        for (int qq = 0; qq < 4; ++qq) {
            const int e = e_base + es * 16 + g * 4 + qq;
            const int r = row[e];
            const float vv = val[e];
#pragma unroll
            for (int nt = 0; nt < NT; ++nt) {
                float y = acc[es][nt][qq];
                y = (y > 0.0f) ? y : __expf(y) - 1.0f;
                atomicAdd(xout + ((size_t)b * NVOUT + r) * COUT + co0 + nt * 16 + b16, vv * y);
            }
        }
}

// Final GEMM partials: part[jblk][b][l] = sum_{j in blk} x4[b][j]*Wf[j][l]
__global__ __launch_bounds__(256)
void final_gemm_partial(const float* __restrict__ x4,   // [16][65536]
                        const float* __restrict__ Wf,   // [65536][256]
                        float* __restrict__ part)       // [256][16][256]
{
    __shared__ float xs[256 * 20];
    const int j0 = blockIdx.x * 256;
    const int t  = threadIdx.x;

#pragma unroll
    for (int it = 0; it < 16; ++it)
        xs[t * 20 + it] = x4[(size_t)it * 65536 + j0 + t];
    __syncthreads();

    float acc[16];
#pragma unroll
    for (int b = 0; b < 16; ++b) acc[b] = 0.0f;

#pragma unroll 4
    for (int jj = 0; jj < 256; ++jj) {
        const float w = Wf[(size_t)(j0 + jj) * 256 + t];
#pragma unroll
        for (int b4 = 0; b4 < 4; ++b4) {
            const float4 xv = *(const float4*)(xs + jj * 20 + b4 * 4);
            acc[b4 * 4 + 0] = fmaf(xv.x, w, acc[b4 * 4 + 0]);
            acc[b4 * 4 + 1] = fmaf(xv.y, w, acc[b4 * 4 + 1]);
            acc[b4 * 4 + 2] = fmaf(xv.z, w, acc[b4 * 4 + 2]);
            acc[b4 * 4 + 3] = fmaf(xv.w, w, acc[b4 * 4 + 3]);
        }
    }
#pragma unroll
    for (int b = 0; b < 16; ++b)
        part[(size_t)blockIdx.x * 4096 + b * 256 + t] = acc[b];
}

__global__ __launch_bounds__(256)
void final_reduce(const float* __restrict__ part, const float* __restrict__ bf,
                  float* __restrict__ out)
{
    const int b = blockIdx.x, l = threadIdx.x;   // 16 x 256
    float s = 0.0f;
    for (int jb = 0; jb < 256; ++jb) s += part[(size_t)jb * 4096 + b * 256 + l];
    out[b * 256 + l] = s + bf[l];
}

extern "C" void kernel_launch(void* const* d_in, const int* in_sizes, int n_in,
                              void* d_out, int out_size, void* d_ws, size_t ws_size,
                              hipStream_t stream)
{
    const float* x    = (const float*)d_in[0];
    const int*   idx0 = (const int*)d_in[1];
    const int*   row0 = (const int*)d_in[2];
    const int*   col0 = (const int*)d_in[3];
    const float* val0 = (const float*)d_in[4];
    const float* W0   = (const float*)d_in[5];
    const float* b0   = (const float*)d_in[6];
    const int*   idx1 = (const int*)d_in[7];
    const int*   row1 = (const int*)d_in[8];
    const int*   col1 = (const int*)d_in[9];
    const float* val1 = (const float*)d_in[10];
    const float* W1   = (const float*)d_in[11];
    const float* b1   = (const float*)d_in[12];
    const int*   idx2 = (const int*)d_in[13];
    const int*   row2 = (const int*)d_in[14];
    const int*   col2 = (const int*)d_in[15];
    const float* val2 = (const float*)d_in[16];
    const float* W2   = (const float*)d_in[17];
    const float* b2   = (const float*)d_in[18];
    const int*   idx3 = (const int*)d_in[19];
    const int*   row3 = (const int*)d_in[20];
    const int*   col3 = (const int*)d_in[21];
    const float* val3 = (const float*)d_in[22];
    const float* W3   = (const float*)d_in[23];
    const float* b3   = (const float*)d_in[24];
    const float* Wf   = (const float*)d_in[25];
    const float* bf   = (const float*)d_in[26];
    float* out = (float*)d_out;

    float* ws = (float*)d_ws;
    // Aliased timeline (float offsets), total 51.9 MB (same envelope as R5/R6):
    float* x1   = ws + 0;         // [16][16384][32]  live L0->L1
    float* x2   = ws + 8388608;   // [16][4096][64]   live L1->L2
    float* x3   = ws + 0;         // [16][1024][128]  live L2->L3 (x1 dead)
    float* x4   = ws + 2097152;   // [16][256][256]   live L3->final
    float* part = ws + 3145728;   // [256][16][256]   final phase
    unsigned short* wt = (unsigned short*)(ws + 12582912);
    unsigned short *WTh0 = wt,          *WTl0 = wt + 2048;
    unsigned short *WTh1 = wt + 4096,   *WTl1 = wt + 22528;
    unsigned short *WTh2 = wt + 40960,  *WTl2 = wt + 114688;
    unsigned short *WTh3 = wt + 188416, *WTl3 = wt + 483328;  // end 778240 u16

    // weight prep (K = 64 / 288 / 576 / 1152)
    wt_prep<3,   4,  32,   64><<<   8, 256, 0, stream>>>(W0, WTh0, WTl0);
    wt_prep<32,  32, 64,  288><<<  72, 256, 0, stream>>>(W1, WTh1, WTl1);
    wt_prep<64,  64, 128, 576><<< 288, 256, 0, stream>>>(W2, WTh2, WTl2);
    wt_prep<128, 128, 256, 1152><<<1152, 256, 0, stream>>>(W3, WTh3, WTl3);

    // L0: x [16][65536][3] -> x1; nnz=49152, ES=2, CS=1, BPB=384
    hipMemsetAsync(x1, 0, (size_t)8388608 * 4, stream);
    conv_pool_mfma<3, 4, 32, 64, 2, 1, 384><<<6144, 256, 0, stream>>>(
        x, idx0, col0, row0, val0, WTh0, WTl0, b0, x1, 65536, 16384);

    // L1: x1 -> x2; nnz=12288, ES=4, CS=1, BPB=48
    hipMemsetAsync(x2, 0, (size_t)4194304 * 4, stream);
    conv_pool_mfma<32, 32, 64, 288, 4, 1, 48><<<768, 256, 0, stream>>>(
        x1, idx1, col1, row1, val1, WTh1, WTl1, b1, x2, 16384, 4096);

    // L2 + L3 (x1 dead -> zero x3|x4 region in one memset)
    hipMemsetAsync(x3, 0, (size_t)3145728 * 4, stream);
    // L2: nnz=3072, ES=4, CS=2, BPB=24
    conv_pool_mfma<64, 64, 128, 576, 4, 2, 24><<<384, 256, 0, stream>>>(
        x2, idx2, col2, row2, val2, WTh2, WTl2, b2, x3, 4096, 1024);
    // L3: nnz=768, ES=4, CS=4, BPB=12
    conv_pool_mfma<128, 128, 256, 1152, 4, 4, 12><<<192, 256, 0, stream>>>(
        x3, idx3, col3, row3, val3, WTh3, WTl3, b3, x4, 1024, 256);

    // final GEMM: out[16,256] = bf + x4_flat[16,65536] @ Wf[65536,256]
    final_gemm_partial<<<256, 256, 0, stream>>>(x4, Wf, part);
    final_reduce<<<16, 256, 0, stream>>>(part, bf, out);
}